// Round 4
// baseline (796.978 us; speedup 1.0000x reference)
//
#include <hip/hip_runtime.h>
#include <math.h>

// ---------------- problem constants ----------------
#define BB 16
#define NBOX 588          // A * 14 * 14
#define TOPJ 392          // J
#define TOPK 196          // K
#define EMBED 768
#define NBLK 128          // bn-stats partial blocks

// ================= fused weight transform (1 launch) =================
// conv-order  (for direct convs):  dst[(ic*KK+tap)*Cout+oc] = src[(oc*Cin+ic)*KK+tap]
// gemm-order  (for GEMM convs):    dst[(tap*Cin+ic)*Cout+oc] = src[(oc*Cin+ic)*KK+tap]
// rw4-order   (for score conv):    dst[(oc*9+tap)*256+ic]    = src[(oc*256+ic)*9+tap]
__device__ inline void tr_conv(const float* s, float* d, int i, int Cout, int Cin, int KK) {
    int oc = i % Cout; int k = i / Cout; int tap = k % KK; int ic = k / KK;
    d[i] = s[(oc * Cin + ic) * KK + tap];
}
__device__ inline void tr_gemm(const float* s, float* d, int i, int Cout, int Cin, int KK) {
    int oc = i % Cout; int t = i / Cout; int ic = t % Cin; int tap = t / Cin;
    d[i] = s[(oc * Cin + ic) * KK + tap];
}
__global__ void w_trans_all(const float* __restrict__ rw1, const float* __restrict__ rw2,
                            const float* __restrict__ rw3, const float* __restrict__ rw4,
                            const float* __restrict__ pw1, const float* __restrict__ pw2,
                            const float* __restrict__ pw3,
                            float* t1, float* t2, float* t3, float* t4,
                            float* q1, float* q2, float* q3) {
    int i = blockIdx.x * 256 + threadIdx.x;
    // sizes: 1728, 73728, 294912, 6912, 3072, 32768, 393216
    if (i < 1728) { tr_conv(rw1, t1, i, 64, 3, 9); return; }
    i -= 1728;
    if (i < 73728) { tr_gemm(rw2, t2, i, 128, 64, 9); return; }
    i -= 73728;
    if (i < 294912) { tr_gemm(rw3, t3, i, 256, 128, 9); return; }
    i -= 294912;
    if (i < 6912) {
        int ic = i % 256; int t = i / 256; int tap = t % 9; int oc = t / 9;
        t4[i] = rw4[(oc * 256 + ic) * 9 + tap];
        return;
    }
    i -= 6912;
    if (i < 3072) { tr_conv(pw1, q1, i, 64, 3, 16); return; }
    i -= 3072;
    if (i < 32768) { tr_gemm(pw2, q2, i, 128, 64, 4); return; }
    i -= 32768;
    if (i < 393216) { tr_gemm(pw3, q3, i, 768, 128, 4); return; }
}

// ================= direct conv, NCHW in (3ch), NHWC out =================
template<int KH, int KW, int S, int P, int OCT>
__global__ __launch_bounds__(256) void conv_direct_nhwc(
    const float* __restrict__ in, const float* __restrict__ wT,
    const float* __restrict__ bias, float* __restrict__ out,
    int Cin, int Hin, int Win, int Cout, int Hout, int Wout)
{
    const int hw = Hout * Wout;
    const long total = (long)BB * hw;
    long sp = (long)blockIdx.x * 256 + threadIdx.x;
    if (sp >= total) return;
    int b  = (int)(sp / hw);
    int r  = (int)(sp - (long)b * hw);
    int oy = r / Wout;
    int ox = r - oy * Wout;
    int oc0 = blockIdx.y * OCT;

    float acc[OCT];
#pragma unroll
    for (int i = 0; i < OCT; ++i) acc[i] = bias[oc0 + i];

    int  ixc[KW]; long yoff[KH]; float xm[KW], ym[KH];
#pragma unroll
    for (int kx = 0; kx < KW; ++kx) {
        int ix = ox * S - P + kx;
        xm[kx] = (ix >= 0 && ix < Win) ? 1.f : 0.f;
        ixc[kx] = min(max(ix, 0), Win - 1);
    }
#pragma unroll
    for (int ky = 0; ky < KH; ++ky) {
        int iy = oy * S - P + ky;
        ym[ky] = (iy >= 0 && iy < Hin) ? 1.f : 0.f;
        yoff[ky] = (long)min(max(iy, 0), Hin - 1) * Win;
    }

    const float* ib = in + (long)b * Cin * Hin * Win;
    for (int ic = 0; ic < Cin; ++ic) {
        const float* ip = ib + (long)ic * Hin * Win;
#pragma unroll
        for (int ky = 0; ky < KH; ++ky) {
            const float* row = ip + yoff[ky];
#pragma unroll
            for (int kx = 0; kx < KW; ++kx) {
                float v = row[ixc[kx]];
                if (P > 0) v *= ym[ky] * xm[kx];
                const float* wr = wT + ((long)((ic * KH + ky) * KW + kx)) * Cout + oc0;
#pragma unroll
                for (int i = 0; i < OCT; ++i) acc[i] = fmaf(v, wr[i], acc[i]);
            }
        }
    }
    float* op = out + sp * Cout + oc0;
#pragma unroll
    for (int i = 0; i < OCT; i += 4) {
        float4 v = {acc[i], acc[i+1], acc[i+2], acc[i+3]};
        *reinterpret_cast<float4*>(op + i) = v;
    }
}

// ================= NHWC tiled GEMM conv =================
// out[M][N] = im2col(in)[M][K] * wT[K][N]; M=B*Ho*Wo (NHWC rows), N=Cout,
// K=(ky,kx,ic) with Cin = 1<<CLOG. BM=64 x BN=64 x BK=32, 256 thr, 4x4/thread,
// double-buffered LDS, prefetch-before-compute. gridDim.z = K splits.
// FUSE: v = relu(v*scale[ic]+shift[ic]) (coef staged in LDS), then pad-mask.
#define GBM 64
#define GBN 64
#define GBK 32
template<int KH, int KW, int S, int P, int CLOG, bool FUSE>
__global__ __launch_bounds__(256) void conv_gemm_nhwc(
    const float* __restrict__ in, const float* __restrict__ wT,
    const float* __restrict__ bias, const float* __restrict__ coef,
    float* __restrict__ out,
    int Hin, int Win, int Cout, int Hout, int Wout)
{
    const int Cin = 1 << CLOG;
    const int hw = Hout * Wout;
    const long Mtot = (long)BB * hw;
    const int Ktot = Cin * KH * KW;
    const int Kc = Ktot / gridDim.z;
    const int k0 = blockIdx.z * Kc;
    const int n0 = blockIdx.y * GBN;
    const long m0 = (long)blockIdx.x * GBM;

    __shared__ float As[2][GBK][GBM];
    __shared__ float Bs[2][GBK][GBN];
    __shared__ float csc[256], csh[256];

    const int tid = threadIdx.x;
    if (FUSE) {
        for (int c = tid; c < Cin; c += 256) { csc[c] = coef[c]; csh[c] = coef[Cin + c]; }
        __syncthreads();
    }

    // A-gather ids: 64 spatial x 4 ic-groups of 8
    const int spl = tid & 63;
    const int icg = tid >> 6;
    long sp_g = m0 + spl;
    const int gb  = (int)(sp_g / hw);
    const int gr  = (int)(sp_g - (long)gb * hw);
    const int goy = gr / Wout;
    const int gox = gr - goy * Wout;
    const float* ibase = in + (long)gb * Hin * Win * Cin;
    // B-gather ids: 64 oc x 4 k-groups of 8
    const int ocl = tid & 63;
    const int kg  = tid >> 6;

    float ra[8], rb[8];

    auto gatherA = [&](int kbase) {
        int tap = kbase >> CLOG;
        int ky = tap / KW, kx = tap - ky * KW;
        int icb = (kbase & (Cin - 1)) + icg * 8;
        int iy = goy * S - P + ky;
        int ix = gox * S - P + kx;
        float mval = 1.f;
        if (P > 0) {
            mval = (iy >= 0 && iy < Hin && ix >= 0 && ix < Win) ? 1.f : 0.f;
            iy = min(max(iy, 0), Hin - 1);
            ix = min(max(ix, 0), Win - 1);
        }
        const float* p = ibase + ((long)iy * Win + ix) * Cin + icb;
        float4 v0 = *reinterpret_cast<const float4*>(p);
        float4 v1 = *reinterpret_cast<const float4*>(p + 4);
        ra[0]=v0.x; ra[1]=v0.y; ra[2]=v0.z; ra[3]=v0.w;
        ra[4]=v1.x; ra[5]=v1.y; ra[6]=v1.z; ra[7]=v1.w;
        if (FUSE) {
#pragma unroll
            for (int j = 0; j < 8; ++j)
                ra[j] = fmaxf(fmaf(ra[j], csc[icb + j], csh[icb + j]), 0.f);
        }
        if (P > 0) {
#pragma unroll
            for (int j = 0; j < 8; ++j) ra[j] *= mval;
        }
    };
    auto gatherB = [&](int kbase) {
#pragma unroll
        for (int j = 0; j < 8; ++j) {
            int k = kbase + kg * 8 + j;
            rb[j] = wT[(long)k * Cout + n0 + ocl];
        }
    };
    auto stage = [&](int buf) {
#pragma unroll
        for (int j = 0; j < 8; ++j) As[buf][icg * 8 + j][spl] = ra[j];
#pragma unroll
        for (int j = 0; j < 8; ++j) Bs[buf][kg * 8 + j][ocl] = rb[j];
    };

    const int tx = tid & 15;        // 4 oc
    const int ty = tid >> 4;        // 4 m
    float acc[4][4];
    if (blockIdx.z == 0) {
        float4 bv = *reinterpret_cast<const float4*>(bias + n0 + tx * 4);
#pragma unroll
        for (int m = 0; m < 4; ++m) {
            acc[m][0] = bv.x; acc[m][1] = bv.y; acc[m][2] = bv.z; acc[m][3] = bv.w;
        }
    } else {
#pragma unroll
        for (int m = 0; m < 4; ++m)
#pragma unroll
            for (int n = 0; n < 4; ++n) acc[m][n] = 0.f;
    }

    const int nch = Kc / GBK;
    gatherA(k0); gatherB(k0);
    stage(0);
    __syncthreads();

    for (int kc = 0; kc < nch; ++kc) {
        int cur = kc & 1;
        if (kc + 1 < nch) { gatherA(k0 + (kc + 1) * GBK); gatherB(k0 + (kc + 1) * GBK); }
#pragma unroll
        for (int kk = 0; kk < GBK; ++kk) {
            float4 a = *reinterpret_cast<const float4*>(&As[cur][kk][ty * 4]);
            float4 bv = *reinterpret_cast<const float4*>(&Bs[cur][kk][tx * 4]);
            float av[4] = {a.x, a.y, a.z, a.w};
            float bw[4] = {bv.x, bv.y, bv.z, bv.w};
#pragma unroll
            for (int m = 0; m < 4; ++m)
#pragma unroll
                for (int n = 0; n < 4; ++n)
                    acc[m][n] = fmaf(av[m], bw[n], acc[m][n]);
        }
        if (kc + 1 < nch) stage(cur ^ 1);
        __syncthreads();
    }

    const long obase = (long)blockIdx.z * (Mtot * Cout);
#pragma unroll
    for (int m = 0; m < 4; ++m) {
        long sp = m0 + ty * 4 + m;
        float4 v = {acc[m][0], acc[m][1], acc[m][2], acc[m][3]};
        *reinterpret_cast<float4*>(out + obase + sp * Cout + n0 + tx * 4) = v;
    }
}

// ================= deterministic partial reduce (float4) =================
__global__ void reduce_parts4(const float4* __restrict__ part, float4* __restrict__ out,
                              long n4, int nz, long stride4) {
    long i = (long)blockIdx.x * 256 + threadIdx.x;
    if (i >= n4) return;
    float4 s = part[i];
    for (int z = 1; z < nz; ++z) {
        float4 p = part[(long)z * stride4 + i];
        s.x += p.x; s.y += p.y; s.z += p.z; s.w += p.w;
    }
    out[i] = s;
}

// ================= BN stats over NHWC (deterministic 2-stage) =================
__global__ void bn_stats_nhwc(const float* __restrict__ x, float* __restrict__ psum,
                              float* __restrict__ psq, int C, int CLOG, long R) {
    const int C4 = C >> 2;
    const int tid = threadIdx.x;
    const int c4 = tid & (C4 - 1);
    const int rg = tid >> (CLOG - 2);
    const int rpb = 256 >> (CLOG - 2);
    float4 s = {0.f, 0.f, 0.f, 0.f}, q = {0.f, 0.f, 0.f, 0.f};
    for (long r = (long)blockIdx.x * rpb + rg; r < R; r += (long)gridDim.x * rpb) {
        float4 v = *reinterpret_cast<const float4*>(x + r * C + c4 * 4);
        s.x += v.x; s.y += v.y; s.z += v.z; s.w += v.w;
        q.x += v.x * v.x; q.y += v.y * v.y; q.z += v.z * v.z; q.w += v.w * v.w;
    }
    __shared__ float4 sd[256], qd[256];
    sd[tid] = s; qd[tid] = q;
    __syncthreads();
    if (tid < C4) {
        float4 S = sd[tid], Q = qd[tid];
        for (int g = 1; g < rpb; ++g) {
            float4 a = sd[tid + g * C4], b = qd[tid + g * C4];
            S.x += a.x; S.y += a.y; S.z += a.z; S.w += a.w;
            Q.x += b.x; Q.y += b.y; Q.z += b.z; Q.w += b.w;
        }
        float Sv[4] = {S.x, S.y, S.z, S.w}, Qv[4] = {Q.x, Q.y, Q.z, Q.w};
        for (int l = 0; l < 4; ++l) {
            psum[(long)(tid * 4 + l) * NBLK + blockIdx.x] = Sv[l];
            psq [(long)(tid * 4 + l) * NBLK + blockIdx.x] = Qv[l];
        }
    }
}

__global__ void bn_coef(const float* __restrict__ psum, const float* __restrict__ psq,
                        const float* __restrict__ gamma, const float* __restrict__ beta,
                        float* __restrict__ coef, int C, float inv_cnt) {
    int c = threadIdx.x;
    if (c >= C) return;
    float s = 0.f, q = 0.f;
    for (int p = 0; p < NBLK; ++p) { s += psum[(long)c * NBLK + p]; q += psq[(long)c * NBLK + p]; }
    float mean = s * inv_cnt;
    float var  = q * inv_cnt - mean * mean;
    float sc = gamma[c] * rsqrtf(var + 1e-5f);
    coef[c] = sc;
    coef[C + c] = beta[c] - mean * sc;
}

// ================= score conv (rp4): tap-parallel partials + reduce =================
// r3 NHWC (16,28,28,256); wT4[(oc*9+tap)*256+ic]; part[tap*3136+sp][oc]
__global__ void score_partial(const float* __restrict__ r3, const float* __restrict__ wT4,
                              const float* __restrict__ coef, float* __restrict__ part) {
    int idx = blockIdx.x * 256 + threadIdx.x;
    if (idx >= 9 * 3136) return;
    int tap = idx / 3136;
    int sp  = idx - tap * 3136;
    int b = sp / 196; int pos = sp - b * 196;
    int oy = pos / 14, ox = pos - oy * 14;
    int ky = tap / 3, kx = tap - ky * 3;
    int iy = oy * 2 - 1 + ky, ix = ox * 2 - 1 + kx;
    float mval = (iy >= 0 && iy < 28 && ix >= 0 && ix < 28) ? 1.f : 0.f;
    iy = min(max(iy, 0), 27); ix = min(max(ix, 0), 27);
    const float* p = r3 + ((long)(b * 28 + iy) * 28 + ix) * 256;
    float a0 = 0.f, a1 = 0.f, a2 = 0.f;
    for (int icv = 0; icv < 64; ++icv) {
        float4 v  = *reinterpret_cast<const float4*>(p + icv * 4);
        float4 sc = *reinterpret_cast<const float4*>(coef + icv * 4);
        float4 sh = *reinterpret_cast<const float4*>(coef + 256 + icv * 4);
        float u[4];
        u[0] = fmaxf(fmaf(v.x, sc.x, sh.x), 0.f);
        u[1] = fmaxf(fmaf(v.y, sc.y, sh.y), 0.f);
        u[2] = fmaxf(fmaf(v.z, sc.z, sh.z), 0.f);
        u[3] = fmaxf(fmaf(v.w, sc.w, sh.w), 0.f);
        float4 w0 = *reinterpret_cast<const float4*>(wT4 + ((0 * 9 + tap) * 256 + icv * 4));
        float4 w1 = *reinterpret_cast<const float4*>(wT4 + ((1 * 9 + tap) * 256 + icv * 4));
        float4 w2 = *reinterpret_cast<const float4*>(wT4 + ((2 * 9 + tap) * 256 + icv * 4));
        a0 += u[0]*w0.x + u[1]*w0.y + u[2]*w0.z + u[3]*w0.w;
        a1 += u[0]*w1.x + u[1]*w1.y + u[2]*w1.z + u[3]*w1.w;
        a2 += u[0]*w2.x + u[1]*w2.y + u[2]*w2.z + u[3]*w2.w;
    }
    part[idx * 3 + 0] = a0 * mval;
    part[idx * 3 + 1] = a1 * mval;
    part[idx * 3 + 2] = a2 * mval;
}

__global__ void score_reduce(const float* __restrict__ part, const float* __restrict__ rb4,
                             float* __restrict__ score) {
    int idx = blockIdx.x * 256 + threadIdx.x;   // 3136*3
    if (idx >= 9408) return;
    int sp = idx / 3; int oc = idx - sp * 3;
    float s = rb4[oc];
    for (int t = 0; t < 9; ++t) s += part[((long)t * 3136 + sp) * 3 + oc];
    int b = sp / 196, pos = sp - b * 196;
    score[b * NBOX + oc * 196 + pos] = s;
}

// ================= top-K (stable ascending rank) + gate =================
__global__ void topk_kernel(const float* __restrict__ score, int* __restrict__ sel,
                            float* __restrict__ gate) {
    int b = blockIdx.x;
    int tid = threadIdx.x;
    __shared__ float s[NBOX];
    __shared__ float red[4];
    for (int n = tid; n < NBOX; n += blockDim.x) s[n] = score[b * NBOX + n];
    __syncthreads();

    float mx = -3.0e38f;
    for (int n = tid; n < NBOX; n += blockDim.x) mx = fmaxf(mx, s[n]);
    for (int o = 32; o > 0; o >>= 1) mx = fmaxf(mx, __shfl_down(mx, o));
    if ((tid & 63) == 0) red[tid >> 6] = mx;
    __syncthreads();
    mx = fmaxf(fmaxf(red[0], red[1]), fmaxf(red[2], red[3]));
    __syncthreads();

    float se = 0.f;
    for (int n = tid; n < NBOX; n += blockDim.x) se += expf(s[n] - mx);
    for (int o = 32; o > 0; o >>= 1) se += __shfl_down(se, o);
    if ((tid & 63) == 0) red[tid >> 6] = se;
    __syncthreads();
    se = red[0] + red[1] + red[2] + red[3];

    for (int n = tid; n < NBOX; n += blockDim.x) {
        float v = s[n];
        int rank = 0;
        for (int m = 0; m < NBOX; ++m) {
            float u = s[m];
            rank += (u < v) || (u == v && m < n);
        }
        if (rank >= TOPJ) {
            int k = rank - TOPJ;
            float p = expf(v - mx) / se;
            sel [b * TOPK + k] = n;
            gate[b * TOPK + k] = (1.0f - p) + p;
        }
    }
}

// ================= ROI align 1x1 + gate (e3 NHWC) =================
__global__ void roi_gather(const float* __restrict__ e3, const int* __restrict__ sel,
                           const float* __restrict__ gate, float* __restrict__ out) {
    int bk = blockIdx.x;
    int b = bk / TOPK;
    int n = sel[bk];
    float gt = gate[bk];
    int a   = n / 196;
    int pos = n % 196;
    int i = pos / 14;
    int j = pos % 14;
    int S = a + 1;
    float inv_cnt = 1.0f / (float)(S * S);

    __shared__ int   cidx[9][4];
    __shared__ float cw  [9][4];
    if (threadIdx.x == 0) {
        int t = 0;
        for (int p = 0; p < S; ++p) {
            float yy = (float)j - S * 0.5f + p + 0.5f;   // row coord from j
            float yc = fmaxf(yy, 0.0f);
            int yf = (int)floorf(yc);
            int y_lo, y_hi; float ly;
            if (yf >= 13) { y_lo = 13; y_hi = 13; ly = 0.f; }
            else          { y_lo = yf; y_hi = yf + 1; ly = yc - (float)yf; }
            for (int q = 0; q < S; ++q) {
                float xx = (float)i - S * 0.5f + q + 0.5f;  // col coord from i
                float xc = fmaxf(xx, 0.0f);
                int xf = (int)floorf(xc);
                int x_lo, x_hi; float lx;
                if (xf >= 13) { x_lo = 13; x_hi = 13; lx = 0.f; }
                else          { x_lo = xf; x_hi = xf + 1; lx = xc - (float)xf; }
                cidx[t][0] = y_lo * 14 + x_lo;  cw[t][0] = (1.f - ly) * (1.f - lx);
                cidx[t][1] = y_lo * 14 + x_hi;  cw[t][1] = (1.f - ly) * lx;
                cidx[t][2] = y_hi * 14 + x_lo;  cw[t][2] = ly * (1.f - lx);
                cidx[t][3] = y_hi * 14 + x_hi;  cw[t][3] = ly * lx;
                ++t;
            }
        }
    }
    __syncthreads();
    int NS = S * S;
    const float* base = e3 + (long)b * 196 * EMBED;
    for (int c = threadIdx.x; c < EMBED; c += blockDim.x) {
        float acc = 0.f;
        for (int t = 0; t < NS; ++t) {
            acc += cw[t][0] * base[cidx[t][0] * EMBED + c]
                 + cw[t][1] * base[cidx[t][1] * EMBED + c]
                 + cw[t][2] * base[cidx[t][2] * EMBED + c]
                 + cw[t][3] * base[cidx[t][3] * EMBED + c];
        }
        out[(long)bk * EMBED + c] = acc * inv_cnt * gt;
    }
}

// ================= host launch =================
extern "C" void kernel_launch(void* const* d_in, const int* in_sizes, int n_in,
                              void* d_out, int out_size, void* d_ws, size_t ws_size,
                              hipStream_t stream) {
    const float* x   = (const float*)d_in[0];
    const float* pw1 = (const float*)d_in[1];
    const float* pb1 = (const float*)d_in[2];
    const float* pw2 = (const float*)d_in[3];
    const float* pb2 = (const float*)d_in[4];
    const float* pw3 = (const float*)d_in[5];
    const float* pb3 = (const float*)d_in[6];
    const float* rw1 = (const float*)d_in[7];
    const float* rb1 = (const float*)d_in[8];
    const float* g1  = (const float*)d_in[9];
    const float* b1  = (const float*)d_in[10];
    const float* rw2 = (const float*)d_in[11];
    const float* rb2 = (const float*)d_in[12];
    const float* g2  = (const float*)d_in[13];
    const float* b2  = (const float*)d_in[14];
    const float* rw3 = (const float*)d_in[15];
    const float* rb3 = (const float*)d_in[16];
    const float* g3  = (const float*)d_in[17];
    const float* b3  = (const float*)d_in[18];
    const float* rw4 = (const float*)d_in[19];
    const float* rb4 = (const float*)d_in[20];

    float* ws = (float*)d_ws;
    // region A: r1 NHWC (16,112,112,64); then rp3/patch2 partials; then e3
    const long SZ_A = 16L * 112 * 112 * 64;   // 12,845,056
    // region B: r2 NHWC (16,56,56,128); then rp4 partials; then e1; then patch3 partials
    const long SZ_B = 16L * 56 * 56 * 128;    // 6,422,528
    // region C: r3 NHWC (16,28,28,256); then e2
    const long SZ_C = 16L * 28 * 28 * 256;    // 3,211,264
    const long OFF_A = 0;
    const long OFF_B = OFF_A + SZ_A;
    const long OFF_C = OFF_B + SZ_B;
    const long OFF_SCORE = OFF_C + SZ_C;
    const long OFF_PS = OFF_SCORE + 16L * NBOX;
    const long OFF_PQ = OFF_PS + 256L * NBLK;
    const long OFF_CO = OFF_PQ + 256L * NBLK;
    const long OFF_GATE = OFF_CO + 512;
    const long OFF_SEL  = OFF_GATE + 16L * TOPK;

    float* r1 = ws + OFF_A;
    float* r2 = ws + OFF_B;
    float* r3 = ws + OFF_C;
    float* e3 = ws + OFF_A;
    float* e1 = ws + OFF_B;
    float* e2 = ws + OFF_C;
    float* partA = ws + OFF_A;
    float* partB = ws + OFF_B;
    float* score = ws + OFF_SCORE;
    float* psum  = ws + OFF_PS;
    float* psq   = ws + OFF_PQ;
    float* coef  = ws + OFF_CO;
    float* gate  = ws + OFF_GATE;
    int*   sel   = (int*)(ws + OFF_SEL);

    // transposed weights in d_out (fully overwritten by roi_gather)
    float* dout = (float*)d_out;
    float* t_rw1 = dout;                      // 1728
    float* t_rw2 = t_rw1 + 1728;              // 73728
    float* t_rw3 = t_rw2 + 73728;             // 294912
    float* t_rw4 = t_rw3 + 294912;            // 6912
    float* t_pw1 = t_rw4 + 6912;              // 3072
    float* t_pw2 = t_pw1 + 3072;              // 32768
    float* t_pw3 = t_pw2 + 32768;             // 393216  (end 806336 < 2408448)

    const int T = 256;
    w_trans_all<<<3150, T, 0, stream>>>(rw1, rw2, rw3, rw4, pw1, pw2, pw3,
                                        t_rw1, t_rw2, t_rw3, t_rw4, t_pw1, t_pw2, t_pw3);

    // ---- region-proposal path (fp32: argsort order must match) ----
    // rp1: x NCHW -> r1 NHWC (16,112,112,64)
    conv_direct_nhwc<3,3,2,1,8><<<dim3(784, 8), T, 0, stream>>>(
        x, t_rw1, rb1, r1, 3, 224, 224, 64, 112, 112);
    bn_stats_nhwc<<<NBLK, T, 0, stream>>>(r1, psum, psq, 64, 6, 200704);
    bn_coef<<<1, T, 0, stream>>>(psum, psq, g1, b1, coef, 64, 1.0f / 200704.f);

    // rp2: bn1+relu fused -> r2 NHWC (16,56,56,128); grid 784x2 = 1568 blocks
    conv_gemm_nhwc<3,3,2,1,6,true><<<dim3(784, 2, 1), T, 0, stream>>>(
        r1, t_rw2, rb2, coef, r2, 112, 112, 128, 56, 56);
    bn_stats_nhwc<<<NBLK, T, 0, stream>>>(r2, psum, psq, 128, 7, 50176);
    bn_coef<<<1, T, 0, stream>>>(psum, psq, g2, b2, coef, 128, 1.0f / 50176.f);

    // rp3: bn2+relu fused, splitK=2 -> partials region A -> r3 NHWC (16,28,28,256)
    conv_gemm_nhwc<3,3,2,1,7,true><<<dim3(196, 4, 2), T, 0, stream>>>(
        r2, t_rw3, rb3, coef, partA, 56, 56, 256, 28, 28);
    reduce_parts4<<<(3211264/4 + T - 1) / T, T, 0, stream>>>(
        (const float4*)partA, (float4*)r3, 3211264/4, 2, 3211264/4);
    bn_stats_nhwc<<<NBLK, T, 0, stream>>>(r3, psum, psq, 256, 8, 12544);
    bn_coef<<<1, T, 0, stream>>>(psum, psq, g3, b3, coef, 256, 1.0f / 12544.f);

    // rp4 (score): bn3+relu fused, tap-parallel partials (region B, r2 dead)
    score_partial<<<(9 * 3136 + T - 1) / T, T, 0, stream>>>(r3, t_rw4, coef, partB);
    score_reduce<<<(9408 + T - 1) / T, T, 0, stream>>>(partB, rb4, score);

    // top-K + gate
    topk_kernel<<<16, T, 0, stream>>>(score, sel, gate);

    // ---- patch-embed path ----
    // patch1: x NCHW -> e1 NHWC (16,56,56,64)  [region B free]
    conv_direct_nhwc<4,4,4,0,8><<<dim3(196, 8), T, 0, stream>>>(
        x, t_pw1, pb1, e1, 3, 224, 224, 64, 56, 56);
    // patch2: e1 -> e2 NHWC (16,28,28,128), splitK=2, partials region A
    conv_gemm_nhwc<2,2,2,0,6,false><<<dim3(196, 2, 2), T, 0, stream>>>(
        e1, t_pw2, pb2, nullptr, partA, 56, 56, 128, 28, 28);
    reduce_parts4<<<(1605632/4 + T - 1) / T, T, 0, stream>>>(
        (const float4*)partA, (float4*)e2, 1605632/4, 2, 1605632/4);
    // patch3: e2 -> e3 NHWC (16,196,768), splitK=2, partials region B (e1 dead)
    conv_gemm_nhwc<2,2,2,0,7,false><<<dim3(49, 12, 2), T, 0, stream>>>(
        e2, t_pw3, pb3, nullptr, partB, 28, 28, 768, 14, 14);
    reduce_parts4<<<(2408448/4 + T - 1) / T, T, 0, stream>>>(
        (const float4*)partB, (float4*)e3, 2408448/4, 2, 2408448/4);

    // ---- ROI align + gate -> d_out (16,196,768) ----
    roi_gather<<<16 * TOPK, T, 0, stream>>>(e3, sel, gate, dout);
}

// Round 5
// 487.611 us; speedup vs baseline: 1.6345x; 1.6345x over previous
//
#include <hip/hip_runtime.h>
#include <math.h>

// ---------------- problem constants ----------------
#define BB 16
#define NBOX 588          // A * 14 * 14
#define TOPJ 392          // J
#define TOPK 196          // K
#define EMBED 768
#define NBLK 128          // bn-stats partial blocks

typedef unsigned short u16;
typedef unsigned int   u32;
using short8 = __attribute__((ext_vector_type(8))) short;
using f32x4  = __attribute__((ext_vector_type(4))) float;

// ---------------- bf16 split helpers ----------------
__device__ inline u16 rnebf(float x) {
    u32 u = __builtin_bit_cast(u32, x);
    u32 r = u + 0x7fff + ((u >> 16) & 1);
    return (u16)(r >> 16);
}
__device__ inline float bfval(u16 h) {
    u32 u = ((u32)h) << 16;
    return __builtin_bit_cast(float, u);
}
__device__ inline u32 pk(u16 a, u16 b) { return (u32)a | ((u32)b << 16); }

// ================= fused weight transform + split (1 launch) =================
// rw1/pw1: fp32 conv-order [ (ic*KK+tap) ][Cout]
// rw4:     fp32 [ (oc*9+tap) ][256]
// rw2/rw3: 3 bf16 limb planes, layout [oc][tap*Cin+ic]
// pw2/pw3: 2 bf16 limb planes, layout [oc][tap*Cin+ic]
__global__ void w_split_all(
    const float* __restrict__ rw1, const float* __restrict__ rw2,
    const float* __restrict__ rw3, const float* __restrict__ rw4,
    const float* __restrict__ pw1, const float* __restrict__ pw2,
    const float* __restrict__ pw3,
    float* t1, float* t4, float* q1,
    u16* w2h, u16* w2m, u16* w2l,
    u16* w3h, u16* w3m, u16* w3l,
    u16* p2h, u16* p2l, u16* p3h, u16* p3l)
{
    int i = blockIdx.x * 256 + threadIdx.x;
    if (i < 1728) {        // rw1: Cout=64, Cin=3, KK=9 (conv-order fp32)
        int oc = i % 64; int k = i / 64; int tap = k % 9; int ic = k / 9;
        t1[i] = rw1[(oc * 3 + ic) * 9 + tap];
        return;
    }
    i -= 1728;
    if (i < 73728) {       // rw2: 128 x (9*64), split3
        int oc = i / 576; int rem = i - oc * 576; int tap = rem >> 6; int ic = rem & 63;
        float v = rw2[(oc * 64 + ic) * 9 + tap];
        u16 h = rnebf(v); float r = v - bfval(h);
        u16 m = rnebf(r); float r2 = r - bfval(m);
        w2h[i] = h; w2m[i] = m; w2l[i] = rnebf(r2);
        return;
    }
    i -= 73728;
    if (i < 294912) {      // rw3: 256 x (9*128), split3
        int oc = i / 1152; int rem = i - oc * 1152; int tap = rem >> 7; int ic = rem & 127;
        float v = rw3[(oc * 128 + ic) * 9 + tap];
        u16 h = rnebf(v); float r = v - bfval(h);
        u16 m = rnebf(r); float r2 = r - bfval(m);
        w3h[i] = h; w3m[i] = m; w3l[i] = rnebf(r2);
        return;
    }
    i -= 294912;
    if (i < 6912) {        // rw4: [oc*9+tap][256] fp32
        int ic = i % 256; int t = i / 256; int tap = t % 9; int oc = t / 9;
        t4[i] = rw4[(oc * 256 + ic) * 9 + tap];
        return;
    }
    i -= 6912;
    if (i < 3072) {        // pw1: Cout=64, Cin=3, KK=16 (conv-order fp32)
        int oc = i % 64; int k = i / 64; int tap = k % 16; int ic = k / 16;
        q1[i] = pw1[(oc * 3 + ic) * 16 + tap];
        return;
    }
    i -= 3072;
    if (i < 32768) {       // pw2: 128 x (4*64), split2
        int oc = i >> 8; int rem = i & 255; int tap = rem >> 6; int ic = rem & 63;
        float v = pw2[(oc * 64 + ic) * 4 + tap];
        u16 h = rnebf(v);
        p2h[i] = h; p2l[i] = rnebf(v - bfval(h));
        return;
    }
    i -= 32768;
    if (i < 393216) {      // pw3: 768 x (4*128), split2
        int oc = i >> 9; int rem = i & 511; int tap = rem >> 7; int ic = rem & 127;
        float v = pw3[(oc * 128 + ic) * 4 + tap];
        u16 h = rnebf(v);
        p3h[i] = h; p3l[i] = rnebf(v - bfval(h));
        return;
    }
}

// ================= direct conv, NCHW in (3ch), NHWC out =================
template<int KH, int KW, int S, int P, int OCT>
__global__ __launch_bounds__(256) void conv_direct_nhwc(
    const float* __restrict__ in, const float* __restrict__ wT,
    const float* __restrict__ bias, float* __restrict__ out,
    int Cin, int Hin, int Win, int Cout, int Hout, int Wout)
{
    const int hw = Hout * Wout;
    const long total = (long)BB * hw;
    long sp = (long)blockIdx.x * 256 + threadIdx.x;
    if (sp >= total) return;
    int b  = (int)(sp / hw);
    int r  = (int)(sp - (long)b * hw);
    int oy = r / Wout;
    int ox = r - oy * Wout;
    int oc0 = blockIdx.y * OCT;

    float acc[OCT];
#pragma unroll
    for (int i = 0; i < OCT; ++i) acc[i] = bias[oc0 + i];

    int  ixc[KW]; long yoff[KH]; float xm[KW], ym[KH];
#pragma unroll
    for (int kx = 0; kx < KW; ++kx) {
        int ix = ox * S - P + kx;
        xm[kx] = (ix >= 0 && ix < Win) ? 1.f : 0.f;
        ixc[kx] = min(max(ix, 0), Win - 1);
    }
#pragma unroll
    for (int ky = 0; ky < KH; ++ky) {
        int iy = oy * S - P + ky;
        ym[ky] = (iy >= 0 && iy < Hin) ? 1.f : 0.f;
        yoff[ky] = (long)min(max(iy, 0), Hin - 1) * Win;
    }

    const float* ib = in + (long)b * Cin * Hin * Win;
    for (int ic = 0; ic < Cin; ++ic) {
        const float* ip = ib + (long)ic * Hin * Win;
#pragma unroll
        for (int ky = 0; ky < KH; ++ky) {
            const float* row = ip + yoff[ky];
#pragma unroll
            for (int kx = 0; kx < KW; ++kx) {
                float v = row[ixc[kx]];
                if (P > 0) v *= ym[ky] * xm[kx];
                const float* wr = wT + ((long)((ic * KH + ky) * KW + kx)) * Cout + oc0;
#pragma unroll
                for (int i = 0; i < OCT; ++i) acc[i] = fmaf(v, wr[i], acc[i]);
            }
        }
    }
    float* op = out + sp * Cout + oc0;
#pragma unroll
    for (int i = 0; i < OCT; i += 4) {
        float4 v = {acc[i], acc[i+1], acc[i+2], acc[i+3]};
        *reinterpret_cast<float4*>(op + i) = v;
    }
}

// ================= split-bf16 MFMA implicit-GEMM conv =================
// C[M][N] = im2col(in)[M][K] * W^T[K][N]; NHWC in/out, K=(tap, ic), Cin=1<<CLOG.
// BM=128 x BN=64 x BK=32; 4 waves as 2x2, wave tile 64x32 via 16x16x32 bf16 MFMA.
// NS limbs (2 or 3); products with limb-level i+j <= NS-1.
// gridDim.z = K-splits (Ktot % (z*32) == 0); z>0 writes partials without bias.
// FUSE: x = relu(x*scale[ic]+shift[ic]) on gathered A, then pad-mask.
#define MBM 128
#define MBN 64
#define MBK 32
#define MLDK 40           // 32 + 8 pad (keeps 16B alignment, 2-way bank alias only)
template<int KH, int KW, int S, int P, int CLOG, bool FUSE, int NS>
__global__ __launch_bounds__(256, 3) void mfma_conv(
    const float* __restrict__ in,
    const u16* __restrict__ w0, const u16* __restrict__ w1, const u16* __restrict__ w2,
    const float* __restrict__ bias, const float* __restrict__ coef,
    float* __restrict__ out,
    int Hin, int Win, int Cout, int Hout, int Wout)
{
    const int Cin = 1 << CLOG;
    const int KK = KH * KW;
    const int Ktot = Cin * KK;
    const int hw = Hout * Wout;
    const long Mtot = (long)BB * hw;
    const int Kc = Ktot / gridDim.z;
    const int kz = blockIdx.z * Kc;
    const int n0 = blockIdx.y * MBN;
    const long m0 = (long)blockIdx.x * MBM;

    __shared__ u16 Asm[NS][MBM * MLDK];
    __shared__ u16 Bsm[NS][MBN * MLDK];
    __shared__ float csc[256], csh[256];

    const int tid = threadIdx.x;
    if (FUSE) {
        for (int c = tid; c < Cin; c += 256) { csc[c] = coef[c]; csh[c] = coef[Cin + c]; }
    }
    __syncthreads();

    // ---- staging ids ----
    const int row_a = tid >> 1;            // 0..127
    const int ca    = (tid & 1) * 16;      // k-offset within chunk
    long sp_g = m0 + row_a; if (sp_g >= Mtot) sp_g = Mtot - 1;
    const int gb  = (int)(sp_g / hw);
    const int gr  = (int)(sp_g - (long)gb * hw);
    const int goy = gr / Wout;
    const int gox = gr - goy * Wout;
    const float* inb = in + (long)gb * Hin * Win * Cin;
    const int row_b = tid >> 2;            // 0..63
    const int cb    = (tid & 3) * 8;
    const int ra_off = row_a * MLDK + ca;
    const int rb_off = row_b * MLDK + cb;
    const u16* wp[3] = {w0, w1, w2};

    u16 ah[NS][16];
    uint4 bu[NS];

    auto gatherA = [&](int k0) {
        int tap = k0 >> CLOG;
        int ky = tap / KW, kx = tap - ky * KW;
        int icb = (k0 & (Cin - 1)) + ca;
        int iy = goy * S - P + ky;
        int ix = gox * S - P + kx;
        float mv = 1.f;
        if (P > 0) {
            mv = (iy >= 0 && iy < Hin && ix >= 0 && ix < Win) ? 1.f : 0.f;
            iy = min(max(iy, 0), Hin - 1);
            ix = min(max(ix, 0), Win - 1);
        }
        const float* p = inb + ((long)iy * Win + ix) * Cin + icb;
        float xv[16];
#pragma unroll
        for (int q = 0; q < 4; ++q) {
            float4 v = *reinterpret_cast<const float4*>(p + q * 4);
            xv[q*4+0] = v.x; xv[q*4+1] = v.y; xv[q*4+2] = v.z; xv[q*4+3] = v.w;
        }
#pragma unroll
        for (int e = 0; e < 16; ++e) {
            float x = xv[e];
            if (FUSE) x = fmaxf(fmaf(x, csc[icb + e], csh[icb + e]), 0.f);
            if (P > 0) x *= mv;
            u16 h = rnebf(x);
            ah[0][e] = h;
            float r = x - bfval(h);
            u16 m = rnebf(r);
            ah[1][e] = m;
            if (NS == 3) { float r2 = r - bfval(m); ah[2][e] = rnebf(r2); }
        }
    };
    auto gatherB = [&](int k0) {
#pragma unroll
        for (int s = 0; s < NS; ++s)
            bu[s] = *reinterpret_cast<const uint4*>(
                wp[s] + (long)(n0 + row_b) * Ktot + k0 + cb);
    };
    auto stage = [&]() {
#pragma unroll
        for (int s = 0; s < NS; ++s) {
            uint4 u0, u1;
            u0.x = pk(ah[s][0],  ah[s][1]);  u0.y = pk(ah[s][2],  ah[s][3]);
            u0.z = pk(ah[s][4],  ah[s][5]);  u0.w = pk(ah[s][6],  ah[s][7]);
            u1.x = pk(ah[s][8],  ah[s][9]);  u1.y = pk(ah[s][10], ah[s][11]);
            u1.z = pk(ah[s][12], ah[s][13]); u1.w = pk(ah[s][14], ah[s][15]);
            *reinterpret_cast<uint4*>(&Asm[s][ra_off])     = u0;
            *reinterpret_cast<uint4*>(&Asm[s][ra_off + 8]) = u1;
            *reinterpret_cast<uint4*>(&Bsm[s][rb_off])     = bu[s];
        }
    };

    // ---- compute ids ----
    const int w  = tid >> 6;
    const int lane = tid & 63;
    const int wr = w >> 1, wc = w & 1;
    const int l15 = lane & 15;
    const int l4k = (lane >> 4) * 8;

    f32x4 acc[4][2];
#pragma unroll
    for (int f = 0; f < 4; ++f)
#pragma unroll
        for (int g = 0; g < 2; ++g) acc[f][g] = (f32x4){0.f, 0.f, 0.f, 0.f};

    const int nch = Kc / MBK;
    for (int c = 0; c < nch; ++c) {
        int k0 = kz + c * MBK;
        gatherA(k0);
        gatherB(k0);
        __syncthreads();      // previous compute done reading LDS
        stage();
        __syncthreads();      // tile staged
        short8 af[4][NS], bfr[2][NS];
#pragma unroll
        for (int f = 0; f < 4; ++f)
#pragma unroll
            for (int s = 0; s < NS; ++s)
                af[f][s] = __builtin_bit_cast(short8,
                    *reinterpret_cast<const uint4*>(&Asm[s][(wr*64 + f*16 + l15)*MLDK + l4k]));
#pragma unroll
        for (int g = 0; g < 2; ++g)
#pragma unroll
            for (int s = 0; s < NS; ++s)
                bfr[g][s] = __builtin_bit_cast(short8,
                    *reinterpret_cast<const uint4*>(&Bsm[s][(wc*32 + g*16 + l15)*MLDK + l4k]));
#pragma unroll
        for (int f = 0; f < 4; ++f)
#pragma unroll
            for (int g = 0; g < 2; ++g) {
                acc[f][g] = __builtin_amdgcn_mfma_f32_16x16x32_bf16(af[f][0], bfr[g][0], acc[f][g], 0, 0, 0);
                acc[f][g] = __builtin_amdgcn_mfma_f32_16x16x32_bf16(af[f][0], bfr[g][1], acc[f][g], 0, 0, 0);
                acc[f][g] = __builtin_amdgcn_mfma_f32_16x16x32_bf16(af[f][1], bfr[g][0], acc[f][g], 0, 0, 0);
                if (NS == 3) {
                    acc[f][g] = __builtin_amdgcn_mfma_f32_16x16x32_bf16(af[f][1], bfr[g][1], acc[f][g], 0, 0, 0);
                    acc[f][g] = __builtin_amdgcn_mfma_f32_16x16x32_bf16(af[f][0], bfr[g][2], acc[f][g], 0, 0, 0);
                    acc[f][g] = __builtin_amdgcn_mfma_f32_16x16x32_bf16(af[f][2], bfr[g][0], acc[f][g], 0, 0, 0);
                }
            }
    }

    // ---- epilogue: C frag layout col=lane&15, row=(lane>>4)*4+reg ----
    const long ob = (long)blockIdx.z * (Mtot * (long)Cout);
    float bv[2];
#pragma unroll
    for (int g = 0; g < 2; ++g) {
        int col = n0 + wc * 32 + g * 16 + l15;
        bv[g] = (blockIdx.z == 0) ? bias[col] : 0.f;
    }
#pragma unroll
    for (int f = 0; f < 4; ++f) {
        long row0 = m0 + wr * 64 + f * 16 + (lane >> 4) * 4;
#pragma unroll
        for (int g = 0; g < 2; ++g) {
            int col = n0 + wc * 32 + g * 16 + l15;
#pragma unroll
            for (int r = 0; r < 4; ++r) {
                long row = row0 + r;
                if (row < Mtot) out[ob + row * Cout + col] = acc[f][g][r] + bv[g];
            }
        }
    }
}

// ================= deterministic partial reduce (float4) =================
__global__ void reduce_parts4(const float4* __restrict__ part, float4* __restrict__ out,
                              long n4, int nz, long stride4) {
    long i = (long)blockIdx.x * 256 + threadIdx.x;
    if (i >= n4) return;
    float4 s = part[i];
    for (int z = 1; z < nz; ++z) {
        float4 p = part[(long)z * stride4 + i];
        s.x += p.x; s.y += p.y; s.z += p.z; s.w += p.w;
    }
    out[i] = s;
}

// ================= BN stats over NHWC (deterministic 2-stage) =================
__global__ void bn_stats_nhwc(const float* __restrict__ x, float* __restrict__ psum,
                              float* __restrict__ psq, int C, int CLOG, long R) {
    const int C4 = C >> 2;
    const int tid = threadIdx.x;
    const int c4 = tid & (C4 - 1);
    const int rg = tid >> (CLOG - 2);
    const int rpb = 256 >> (CLOG - 2);
    float4 s = {0.f, 0.f, 0.f, 0.f}, q = {0.f, 0.f, 0.f, 0.f};
    for (long r = (long)blockIdx.x * rpb + rg; r < R; r += (long)gridDim.x * rpb) {
        float4 v = *reinterpret_cast<const float4*>(x + r * C + c4 * 4);
        s.x += v.x; s.y += v.y; s.z += v.z; s.w += v.w;
        q.x += v.x * v.x; q.y += v.y * v.y; q.z += v.z * v.z; q.w += v.w * v.w;
    }
    __shared__ float4 sd[256], qd[256];
    sd[tid] = s; qd[tid] = q;
    __syncthreads();
    if (tid < C4) {
        float4 S = sd[tid], Q = qd[tid];
        for (int g = 1; g < rpb; ++g) {
            float4 a = sd[tid + g * C4], b = qd[tid + g * C4];
            S.x += a.x; S.y += a.y; S.z += a.z; S.w += a.w;
            Q.x += b.x; Q.y += b.y; Q.z += b.z; Q.w += b.w;
        }
        float Sv[4] = {S.x, S.y, S.z, S.w}, Qv[4] = {Q.x, Q.y, Q.z, Q.w};
        for (int l = 0; l < 4; ++l) {
            psum[(long)(tid * 4 + l) * NBLK + blockIdx.x] = Sv[l];
            psq [(long)(tid * 4 + l) * NBLK + blockIdx.x] = Qv[l];
        }
    }
}

__global__ void bn_coef(const float* __restrict__ psum, const float* __restrict__ psq,
                        const float* __restrict__ gamma, const float* __restrict__ beta,
                        float* __restrict__ coef, int C, float inv_cnt) {
    int c = threadIdx.x;
    if (c >= C) return;
    float s = 0.f, q = 0.f;
    for (int p = 0; p < NBLK; ++p) { s += psum[(long)c * NBLK + p]; q += psq[(long)c * NBLK + p]; }
    float mean = s * inv_cnt;
    float var  = q * inv_cnt - mean * mean;
    float sc = gamma[c] * rsqrtf(var + 1e-5f);
    coef[c] = sc;
    coef[C + c] = beta[c] - mean * sc;
}

// ================= score conv (rp4): tap-parallel partials + reduce =================
__global__ void score_partial(const float* __restrict__ r3, const float* __restrict__ wT4,
                              const float* __restrict__ coef, float* __restrict__ part) {
    int idx = blockIdx.x * 256 + threadIdx.x;
    if (idx >= 9 * 3136) return;
    int tap = idx / 3136;
    int sp  = idx - tap * 3136;
    int b = sp / 196; int pos = sp - b * 196;
    int oy = pos / 14, ox = pos - oy * 14;
    int ky = tap / 3, kx = tap - ky * 3;
    int iy = oy * 2 - 1 + ky, ix = ox * 2 - 1 + kx;
    float mval = (iy >= 0 && iy < 28 && ix >= 0 && ix < 28) ? 1.f : 0.f;
    iy = min(max(iy, 0), 27); ix = min(max(ix, 0), 27);
    const float* p = r3 + ((long)(b * 28 + iy) * 28 + ix) * 256;
    float a0 = 0.f, a1 = 0.f, a2 = 0.f;
    for (int icv = 0; icv < 64; ++icv) {
        float4 v  = *reinterpret_cast<const float4*>(p + icv * 4);
        float4 sc = *reinterpret_cast<const float4*>(coef + icv * 4);
        float4 sh = *reinterpret_cast<const float4*>(coef + 256 + icv * 4);
        float u[4];
        u[0] = fmaxf(fmaf(v.x, sc.x, sh.x), 0.f);
        u[1] = fmaxf(fmaf(v.y, sc.y, sh.y), 0.f);
        u[2] = fmaxf(fmaf(v.z, sc.z, sh.z), 0.f);
        u[3] = fmaxf(fmaf(v.w, sc.w, sh.w), 0.f);
        float4 w0 = *reinterpret_cast<const float4*>(wT4 + ((0 * 9 + tap) * 256 + icv * 4));
        float4 w1 = *reinterpret_cast<const float4*>(wT4 + ((1 * 9 + tap) * 256 + icv * 4));
        float4 w2 = *reinterpret_cast<const float4*>(wT4 + ((2 * 9 + tap) * 256 + icv * 4));
        a0 += u[0]*w0.x + u[1]*w0.y + u[2]*w0.z + u[3]*w0.w;
        a1 += u[0]*w1.x + u[1]*w1.y + u[2]*w1.z + u[3]*w1.w;
        a2 += u[0]*w2.x + u[1]*w2.y + u[2]*w2.z + u[3]*w2.w;
    }
    part[idx * 3 + 0] = a0 * mval;
    part[idx * 3 + 1] = a1 * mval;
    part[idx * 3 + 2] = a2 * mval;
}

__global__ void score_reduce(const float* __restrict__ part, const float* __restrict__ rb4,
                             float* __restrict__ score) {
    int idx = blockIdx.x * 256 + threadIdx.x;   // 3136*3
    if (idx >= 9408) return;
    int sp = idx / 3; int oc = idx - sp * 3;
    float s = rb4[oc];
    for (int t = 0; t < 9; ++t) s += part[((long)t * 3136 + sp) * 3 + oc];
    int b = sp / 196, pos = sp - b * 196;
    score[b * NBOX + oc * 196 + pos] = s;
}

// ================= top-K (stable ascending rank) + gate =================
__global__ void topk_kernel(const float* __restrict__ score, int* __restrict__ sel,
                            float* __restrict__ gate) {
    int b = blockIdx.x;
    int tid = threadIdx.x;
    __shared__ float s[NBOX];
    __shared__ float red[4];
    for (int n = tid; n < NBOX; n += blockDim.x) s[n] = score[b * NBOX + n];
    __syncthreads();

    float mx = -3.0e38f;
    for (int n = tid; n < NBOX; n += blockDim.x) mx = fmaxf(mx, s[n]);
    for (int o = 32; o > 0; o >>= 1) mx = fmaxf(mx, __shfl_down(mx, o));
    if ((tid & 63) == 0) red[tid >> 6] = mx;
    __syncthreads();
    mx = fmaxf(fmaxf(red[0], red[1]), fmaxf(red[2], red[3]));
    __syncthreads();

    float se = 0.f;
    for (int n = tid; n < NBOX; n += blockDim.x) se += expf(s[n] - mx);
    for (int o = 32; o > 0; o >>= 1) se += __shfl_down(se, o);
    if ((tid & 63) == 0) red[tid >> 6] = se;
    __syncthreads();
    se = red[0] + red[1] + red[2] + red[3];

    for (int n = tid; n < NBOX; n += blockDim.x) {
        float v = s[n];
        int rank = 0;
        for (int m = 0; m < NBOX; ++m) {
            float u = s[m];
            rank += (u < v) || (u == v && m < n);
        }
        if (rank >= TOPJ) {
            int k = rank - TOPJ;
            float p = expf(v - mx) / se;
            sel [b * TOPK + k] = n;
            gate[b * TOPK + k] = (1.0f - p) + p;
        }
    }
}

// ================= ROI align 1x1 + gate (e3 NHWC) =================
__global__ void roi_gather(const float* __restrict__ e3, const int* __restrict__ sel,
                           const float* __restrict__ gate, float* __restrict__ out) {
    int bk = blockIdx.x;
    int b = bk / TOPK;
    int n = sel[bk];
    float gt = gate[bk];
    int a   = n / 196;
    int pos = n % 196;
    int i = pos / 14;
    int j = pos % 14;
    int S = a + 1;
    float inv_cnt = 1.0f / (float)(S * S);

    __shared__ int   cidx[9][4];
    __shared__ float cw  [9][4];
    if (threadIdx.x == 0) {
        int t = 0;
        for (int p = 0; p < S; ++p) {
            float yy = (float)j - S * 0.5f + p + 0.5f;   // row coord from j
            float yc = fmaxf(yy, 0.0f);
            int yf = (int)floorf(yc);
            int y_lo, y_hi; float ly;
            if (yf >= 13) { y_lo = 13; y_hi = 13; ly = 0.f; }
            else          { y_lo = yf; y_hi = yf + 1; ly = yc - (float)yf; }
            for (int q = 0; q < S; ++q) {
                float xx = (float)i - S * 0.5f + q + 0.5f;  // col coord from i
                float xc = fmaxf(xx, 0.0f);
                int xf = (int)floorf(xc);
                int x_lo, x_hi; float lx;
                if (xf >= 13) { x_lo = 13; x_hi = 13; lx = 0.f; }
                else          { x_lo = xf; x_hi = xf + 1; lx = xc - (float)xf; }
                cidx[t][0] = y_lo * 14 + x_lo;  cw[t][0] = (1.f - ly) * (1.f - lx);
                cidx[t][1] = y_lo * 14 + x_hi;  cw[t][1] = (1.f - ly) * lx;
                cidx[t][2] = y_hi * 14 + x_lo;  cw[t][2] = ly * (1.f - lx);
                cidx[t][3] = y_hi * 14 + x_hi;  cw[t][3] = ly * lx;
                ++t;
            }
        }
    }
    __syncthreads();
    int NS2 = S * S;
    const float* base = e3 + (long)b * 196 * EMBED;
    for (int c = threadIdx.x; c < EMBED; c += blockDim.x) {
        float acc = 0.f;
        for (int t = 0; t < NS2; ++t) {
            acc += cw[t][0] * base[cidx[t][0] * EMBED + c]
                 + cw[t][1] * base[cidx[t][1] * EMBED + c]
                 + cw[t][2] * base[cidx[t][2] * EMBED + c]
                 + cw[t][3] * base[cidx[t][3] * EMBED + c];
        }
        out[(long)bk * EMBED + c] = acc * inv_cnt * gt;
    }
}

// ================= host launch =================
extern "C" void kernel_launch(void* const* d_in, const int* in_sizes, int n_in,
                              void* d_out, int out_size, void* d_ws, size_t ws_size,
                              hipStream_t stream) {
    const float* x   = (const float*)d_in[0];
    const float* pw1 = (const float*)d_in[1];
    const float* pb1 = (const float*)d_in[2];
    const float* pw2 = (const float*)d_in[3];
    const float* pb2 = (const float*)d_in[4];
    const float* pw3 = (const float*)d_in[5];
    const float* pb3 = (const float*)d_in[6];
    const float* rw1 = (const float*)d_in[7];
    const float* rb1 = (const float*)d_in[8];
    const float* g1  = (const float*)d_in[9];
    const float* b1  = (const float*)d_in[10];
    const float* rw2 = (const float*)d_in[11];
    const float* rb2 = (const float*)d_in[12];
    const float* g2  = (const float*)d_in[13];
    const float* b2  = (const float*)d_in[14];
    const float* rw3 = (const float*)d_in[15];
    const float* rb3 = (const float*)d_in[16];
    const float* g3  = (const float*)d_in[17];
    const float* b3  = (const float*)d_in[18];
    const float* rw4 = (const float*)d_in[19];
    const float* rb4 = (const float*)d_in[20];

    float* ws = (float*)d_ws;
    const long SZ_A = 16L * 112 * 112 * 64;   // 12,845,056
    const long SZ_B = 16L * 56 * 56 * 128;    // 6,422,528
    const long SZ_C = 16L * 28 * 28 * 256;    // 3,211,264
    const long OFF_A = 0;
    const long OFF_B = OFF_A + SZ_A;
    const long OFF_C = OFF_B + SZ_B;
    const long OFF_SCORE = OFF_C + SZ_C;
    const long OFF_PS = OFF_SCORE + 16L * NBOX;
    const long OFF_PQ = OFF_PS + 256L * NBLK;
    const long OFF_CO = OFF_PQ + 256L * NBLK;
    const long OFF_GATE = OFF_CO + 512;
    const long OFF_SEL  = OFF_GATE + 16L * TOPK;

    float* r1 = ws + OFF_A;
    float* r2 = ws + OFF_B;
    float* r3 = ws + OFF_C;
    float* e3 = ws + OFF_A;
    float* e1 = ws + OFF_B;
    float* e2 = ws + OFF_C;
    float* partA = ws + OFF_A;
    float* partB = ws + OFF_B;
    float* score = ws + OFF_SCORE;
    float* psum  = ws + OFF_PS;
    float* psq   = ws + OFF_PQ;
    float* coef  = ws + OFF_CO;
    float* gate  = ws + OFF_GATE;
    int*   sel   = (int*)(ws + OFF_SEL);

    // weight scratch in d_out (fully overwritten by roi_gather at the end)
    float* dout = (float*)d_out;
    float* t_rw1 = dout;                        // 1728 f32
    float* t_rw4 = dout + 1728;                 // 6912 f32
    float* q_pw1 = dout + 8640;                 // 3072 f32 -> end 11712
    u16* w2h = (u16*)(dout + 11712);            // 73728 u16 each
    u16* w2m = (u16*)(dout + 48576);
    u16* w2l = (u16*)(dout + 85440);
    u16* w3h = (u16*)(dout + 122304);           // 294912 u16 each
    u16* w3m = (u16*)(dout + 269760);
    u16* w3l = (u16*)(dout + 417216);
    u16* p2h = (u16*)(dout + 564672);           // 32768 u16 each
    u16* p2l = (u16*)(dout + 581056);
    u16* p3h = (u16*)(dout + 597440);           // 393216 u16 each
    u16* p3l = (u16*)(dout + 794048);           // end 990656 < 2408448

    const int T = 256;
    w_split_all<<<3150, T, 0, stream>>>(rw1, rw2, rw3, rw4, pw1, pw2, pw3,
                                        t_rw1, t_rw4, q_pw1,
                                        w2h, w2m, w2l, w3h, w3m, w3l,
                                        p2h, p2l, p3h, p3l);

    // ---- region-proposal path (3-limb split: fp32-class accuracy for argsort) ----
    // rp1: x NCHW -> r1 NHWC (16,112,112,64)
    conv_direct_nhwc<3,3,2,1,8><<<dim3(784, 8), T, 0, stream>>>(
        x, t_rw1, rb1, r1, 3, 224, 224, 64, 112, 112);
    bn_stats_nhwc<<<NBLK, T, 0, stream>>>(r1, psum, psq, 64, 6, 200704);
    bn_coef<<<1, T, 0, stream>>>(psum, psq, g1, b1, coef, 64, 1.0f / 200704.f);

    // rp2: bn1+relu fused -> r2 NHWC (16,56,56,128); M=50176,K=576,N=128
    mfma_conv<3,3,2,1,6,true,3><<<dim3(392, 2, 1), T, 0, stream>>>(
        r1, w2h, w2m, w2l, rb2, coef, r2, 112, 112, 128, 56, 56);
    bn_stats_nhwc<<<NBLK, T, 0, stream>>>(r2, psum, psq, 128, 7, 50176);
    bn_coef<<<1, T, 0, stream>>>(psum, psq, g2, b2, coef, 128, 1.0f / 50176.f);

    // rp3: bn2+relu fused, splitK=2 -> partials region A -> r3 NHWC (16,28,28,256)
    mfma_conv<3,3,2,1,7,true,3><<<dim3(98, 4, 2), T, 0, stream>>>(
        r2, w3h, w3m, w3l, rb3, coef, partA, 56, 56, 256, 28, 28);
    reduce_parts4<<<(3211264/4 + T - 1) / T, T, 0, stream>>>(
        (const float4*)partA, (float4*)r3, 3211264/4, 2, 3211264/4);
    bn_stats_nhwc<<<NBLK, T, 0, stream>>>(r3, psum, psq, 256, 8, 12544);
    bn_coef<<<1, T, 0, stream>>>(psum, psq, g3, b3, coef, 256, 1.0f / 12544.f);

    // rp4 (score): bn3+relu fused, tap-parallel partials (region B, r2 dead)
    score_partial<<<(9 * 3136 + T - 1) / T, T, 0, stream>>>(r3, t_rw4, coef, partB);
    score_reduce<<<(9408 + T - 1) / T, T, 0, stream>>>(partB, rb4, score);

    // top-K + gate
    topk_kernel<<<16, T, 0, stream>>>(score, sel, gate);

    // ---- patch-embed path (2-limb split: output tolerance is bf16-scale) ----
    // patch1: x NCHW -> e1 NHWC (16,56,56,64)  [region B free]
    conv_direct_nhwc<4,4,4,0,8><<<dim3(196, 8), T, 0, stream>>>(
        x, q_pw1, pb1, e1, 3, 224, 224, 64, 56, 56);
    // patch2: e1 -> e2 NHWC (16,28,28,128); M=12544,K=256, splitK=2, partials A
    mfma_conv<2,2,2,0,6,false,2><<<dim3(98, 2, 2), T, 0, stream>>>(
        e1, p2h, p2l, nullptr, pb2, nullptr, partA, 56, 56, 128, 28, 28);
    reduce_parts4<<<(1605632/4 + T - 1) / T, T, 0, stream>>>(
        (const float4*)partA, (float4*)e2, 1605632/4, 2, 1605632/4);
    // patch3: e2 -> e3 NHWC (16,196,768); M=3136,K=512, splitK=2, partials B (e1 dead)
    mfma_conv<2,2,2,0,7,false,2><<<dim3(25, 12, 2), T, 0, stream>>>(
        e2, p3h, p3l, nullptr, pb3, nullptr, partB, 28, 28, 768, 14, 14);
    reduce_parts4<<<(2408448/4 + T - 1) / T, T, 0, stream>>>(
        (const float4*)partB, (float4*)e3, 2408448/4, 2, 2408448/4);

    // ---- ROI align + gate -> d_out (16,196,768) ----
    roi_gather<<<16 * TOPK, T, 0, stream>>>(e3, sel, gate, dout);
}